// Round 6
// baseline (652.652 us; speedup 1.0000x reference)
//
#include <hip/hip_runtime.h>

#define N_NODES 200000
#define N_EDGES 5000000
#define N_GRAPHS 1024
#define HID 16
#define ALPHA 0.2f

#define BSH 7
#define BSZ 128                      // nodes per bucket
#define NB 1563                      // ceil(N_NODES / BSZ)
#define NWGB 256                     // build workgroups
#define EPB ((N_EDGES + NWGB - 1) / NWGB)  // 19532 (divisible by 4)

#define SACCP 20                     // LDS stride (floats) for staging, 16B-aligned

// ===========================================================================
// BUILD stage 1: counting sort of edges by dst >> 7 into packed (src<<7|dl)
// M layout is WG-major: M[w * NB + b]  (all accesses coalesced)
// ===========================================================================
__global__ void count_kernel(const int* __restrict__ dst, int* __restrict__ M) {
    __shared__ int hist[NB];
    for (int i = threadIdx.x; i < NB; i += 256) hist[i] = 0;
    __syncthreads();
    int base = blockIdx.x * EPB;
    int end = min(base + EPB, N_EDGES);
    for (int e = base + threadIdx.x * 4; e < end; e += 256 * 4) {
        int4 d4 = *reinterpret_cast<const int4*>(dst + e);
        atomicAdd(&hist[d4.x >> BSH], 1);
        atomicAdd(&hist[d4.y >> BSH], 1);
        atomicAdd(&hist[d4.z >> BSH], 1);
        atomicAdd(&hist[d4.w >> BSH], 1);
    }
    __syncthreads();
    for (int i = threadIdx.x; i < NB; i += 256)
        M[blockIdx.x * NB + i] = hist[i];
}

__global__ void colscan_kernel(int* __restrict__ M, int* __restrict__ col_total) {
    int b = blockIdx.x * blockDim.x + threadIdx.x;
    if (b >= NB) return;
    int run = 0;
#pragma unroll 8
    for (int w = 0; w < NWGB; ++w) {
        int v = M[w * NB + b];      // coalesced across threads
        M[w * NB + b] = run;
        run += v;
    }
    col_total[b] = run;
}

__global__ void bucketscan_kernel(const int* __restrict__ col_total,
                                  int* __restrict__ bucket_base) {
    __shared__ int sc[256];
    int t = threadIdx.x;
    int v[7];
    int s = 0;
#pragma unroll
    for (int k = 0; k < 7; ++k) {
        int i = t * 7 + k;
        v[k] = (i < NB) ? col_total[i] : 0;
        s += v[k];
    }
    sc[t] = s;
    __syncthreads();
    for (int off = 1; off < 256; off <<= 1) {
        int tmp = (t >= off) ? sc[t - off] : 0;
        __syncthreads();
        sc[t] += tmp;
        __syncthreads();
    }
    int excl = sc[t] - s;
#pragma unroll
    for (int k = 0; k < 7; ++k) {
        int i = t * 7 + k;
        if (i < NB) bucket_base[i] = excl;
        excl += v[k];
    }
    if (t == 255) bucket_base[NB] = sc[255];
}

__global__ void scatter_build_kernel(const int* __restrict__ src,
                                     const int* __restrict__ dst,
                                     const int* __restrict__ M,
                                     const int* __restrict__ bucket_base,
                                     int* __restrict__ packed) {
    __shared__ int cur[NB];
    int w = blockIdx.x;
    for (int i = threadIdx.x; i < NB; i += 256)
        cur[i] = bucket_base[i] + M[w * NB + i];
    __syncthreads();
    int base = w * EPB;
    int end = min(base + EPB, N_EDGES);
    for (int e = base + threadIdx.x * 4; e < end; e += 256 * 4) {
        int4 s4 = *reinterpret_cast<const int4*>(src + e);
        int4 d4 = *reinterpret_cast<const int4*>(dst + e);
        int p;
        p = atomicAdd(&cur[d4.x >> BSH], 1); packed[p] = (s4.x << BSH) | (d4.x & (BSZ - 1));
        p = atomicAdd(&cur[d4.y >> BSH], 1); packed[p] = (s4.y << BSH) | (d4.y & (BSZ - 1));
        p = atomicAdd(&cur[d4.z >> BSH], 1); packed[p] = (s4.z << BSH) | (d4.z & (BSZ - 1));
        p = atomicAdd(&cur[d4.w >> BSH], 1); packed[p] = (s4.w << BSH) | (d4.w & (BSZ - 1));
    }
}

// ===========================================================================
// BUILD stage 2 + layer-0 aggregation fused: per-bucket count/scan/scatter
// -> CSR (row_ptr, sorted_src), plus sum0/deg per node (d=1 gathers are
// L2-resident: x is 800 KB).
// ===========================================================================
__global__ void csr_kernel(const float* __restrict__ x,
                           const int* __restrict__ packed,
                           const int* __restrict__ bucket_base,
                           int* __restrict__ row_ptr,
                           int* __restrict__ sorted_src,
                           float* __restrict__ sum0,
                           float* __restrict__ degf) {
    __shared__ int cnt[BSZ], scn[BSZ], cur[BSZ];
    __shared__ float ssum[BSZ];
    int t = threadIdx.x, b = blockIdx.x;
    if (t < BSZ) { cnt[t] = 0; ssum[t] = 0.0f; }
    __syncthreads();
    int e0 = bucket_base[b], e1 = bucket_base[b + 1];
    for (int i = e0 + t; i < e1; i += 256) {
        int pk = packed[i];
        int dl = pk & (BSZ - 1);
        atomicAdd(&cnt[dl], 1);
        atomicAdd(&ssum[dl], x[pk >> BSH]);
    }
    __syncthreads();
    if (t < BSZ) scn[t] = cnt[t];
    __syncthreads();
    for (int off = 1; off < BSZ; off <<= 1) {
        int v = 0;
        if (t < BSZ && t >= off) v = scn[t - off];
        __syncthreads();
        if (t < BSZ) scn[t] += v;
        __syncthreads();
    }
    if (t < BSZ) {
        int node = b * BSZ + t;
        int base = e0 + scn[t] - cnt[t];   // exclusive scan
        if (node < N_NODES) {
            row_ptr[node] = base;
            sum0[node] = ssum[t];
            degf[node] = (float)cnt[t];
        }
        cur[t] = base;
    }
    if (b == NB - 1 && t == 0) row_ptr[N_NODES] = N_EDGES;
    __syncthreads();
    for (int i = e0 + t; i < e1; i += 256) {
        int pk = packed[i];
        int p = atomicAdd(&cur[pk & (BSZ - 1)], 1);
        sorted_src[p] = pk >> BSH;
    }
}

// ===========================================================================
// Layer 0 node update (pure streaming): h = relu(mean*Wl+bl+x*Wr); @Wlin+blin
// ===========================================================================
__global__ void node0_kernel(const float* __restrict__ x,
                             const float* __restrict__ sum0,
                             const float* __restrict__ deg,
                             const float* __restrict__ Wl, const float* __restrict__ bl,
                             const float* __restrict__ Wr,
                             const float* __restrict__ Wlin, const float* __restrict__ blin,
                             float* __restrict__ xout) {
    __shared__ float sWl[HID], sWr[HID], sbl[HID], sblin[HID], sWlin[HID * HID];
    if (threadIdx.x < HID) {
        sWl[threadIdx.x] = Wl[threadIdx.x]; sWr[threadIdx.x] = Wr[threadIdx.x];
        sbl[threadIdx.x] = bl[threadIdx.x]; sblin[threadIdx.x] = blin[threadIdx.x];
    }
    if (threadIdx.x < HID * HID) sWlin[threadIdx.x] = Wlin[threadIdx.x];
    __syncthreads();
    int stride = gridDim.x * blockDim.x;
    for (int n = blockIdx.x * blockDim.x + threadIdx.x; n < N_NODES; n += stride) {
        float mean = sum0[n] / fmaxf(deg[n], 1.0f);
        float xv = x[n];
        float h[HID];
#pragma unroll
        for (int j = 0; j < HID; ++j)
            h[j] = fmaxf(mean * sWl[j] + sbl[j] + xv * sWr[j], 0.0f);
#pragma unroll
        for (int j = 0; j < HID; ++j) {
            float acc = sblin[j];
#pragma unroll
            for (int k = 0; k < HID; ++k) acc += h[k] * sWlin[k * HID + j];
            xout[n * HID + j] = acc;
        }
    }
}

// ===========================================================================
// Layers 1/2 (d=16): 4-lane group per node, float4 register accumulation,
// 8 independent cache-line gathers in flight per group per iteration.
// Fused node update via LDS staging. 64 nodes per 256-thread block.
// ===========================================================================
__global__ void layerB_csr(const float* __restrict__ xin,
                           const int* __restrict__ row_ptr,
                           const int* __restrict__ sorted_src,
                           const float* __restrict__ Wl, const float* __restrict__ bl,
                           const float* __restrict__ Wr,
                           const float* __restrict__ Wlin, const float* __restrict__ blin,
                           float* __restrict__ xout) {
    __shared__ float sacc[64 * SACCP];   // mean vectors, padded stride
    __shared__ float sxv[64 * SACCP];    // self x vectors
    __shared__ float sh[64 * SACCP];     // hidden after relu
    __shared__ float sWl[HID * HID], sWr[HID * HID], sWlin[HID * HID];
    __shared__ float sbl[HID], sblin[HID];
    int t = threadIdx.x;
    if (t < HID * HID) { sWl[t] = Wl[t]; sWr[t] = Wr[t]; sWlin[t] = Wlin[t]; }
    if (t < HID) { sbl[t] = bl[t]; sblin[t] = blin[t]; }
    __syncthreads();

    int q = t & 3;           // feature quad: features 4q..4q+3
    int g = t >> 2;          // group 0..63 -> node
    int n = blockIdx.x * 64 + g;

    if (n < N_NODES) {
        int r0 = row_ptr[n], r1 = row_ptr[n + 1];
        const float* xq = xin + 4 * q;
        float4 acc = make_float4(0.0f, 0.0f, 0.0f, 0.0f);
        int i = r0;
        for (; i + 8 <= r1; i += 8) {
            int s0 = sorted_src[i],     s1 = sorted_src[i + 1];
            int s2 = sorted_src[i + 2], s3 = sorted_src[i + 3];
            int s4 = sorted_src[i + 4], s5 = sorted_src[i + 5];
            int s6 = sorted_src[i + 6], s7 = sorted_src[i + 7];
            float4 g0 = *reinterpret_cast<const float4*>(xq + (size_t)s0 * HID);
            float4 g1 = *reinterpret_cast<const float4*>(xq + (size_t)s1 * HID);
            float4 g2 = *reinterpret_cast<const float4*>(xq + (size_t)s2 * HID);
            float4 g3 = *reinterpret_cast<const float4*>(xq + (size_t)s3 * HID);
            float4 g4 = *reinterpret_cast<const float4*>(xq + (size_t)s4 * HID);
            float4 g5 = *reinterpret_cast<const float4*>(xq + (size_t)s5 * HID);
            float4 g6 = *reinterpret_cast<const float4*>(xq + (size_t)s6 * HID);
            float4 g7 = *reinterpret_cast<const float4*>(xq + (size_t)s7 * HID);
            acc.x += (g0.x + g1.x + g2.x + g3.x) + (g4.x + g5.x + g6.x + g7.x);
            acc.y += (g0.y + g1.y + g2.y + g3.y) + (g4.y + g5.y + g6.y + g7.y);
            acc.z += (g0.z + g1.z + g2.z + g3.z) + (g4.z + g5.z + g6.z + g7.z);
            acc.w += (g0.w + g1.w + g2.w + g3.w) + (g4.w + g5.w + g6.w + g7.w);
        }
        for (; i + 4 <= r1; i += 4) {
            int s0 = sorted_src[i],     s1 = sorted_src[i + 1];
            int s2 = sorted_src[i + 2], s3 = sorted_src[i + 3];
            float4 g0 = *reinterpret_cast<const float4*>(xq + (size_t)s0 * HID);
            float4 g1 = *reinterpret_cast<const float4*>(xq + (size_t)s1 * HID);
            float4 g2 = *reinterpret_cast<const float4*>(xq + (size_t)s2 * HID);
            float4 g3 = *reinterpret_cast<const float4*>(xq + (size_t)s3 * HID);
            acc.x += g0.x + g1.x + g2.x + g3.x;
            acc.y += g0.y + g1.y + g2.y + g3.y;
            acc.z += g0.z + g1.z + g2.z + g3.z;
            acc.w += g0.w + g1.w + g2.w + g3.w;
        }
        for (; i < r1; ++i) {
            float4 gv = *reinterpret_cast<const float4*>(xq + (size_t)sorted_src[i] * HID);
            acc.x += gv.x; acc.y += gv.y; acc.z += gv.z; acc.w += gv.w;
        }
        float invd = 1.0f / fmaxf((float)(r1 - r0), 1.0f);
        acc.x *= invd; acc.y *= invd; acc.z *= invd; acc.w *= invd;
        *reinterpret_cast<float4*>(&sacc[g * SACCP + 4 * q]) = acc;
        *reinterpret_cast<float4*>(&sxv[g * SACCP + 4 * q]) =
            *reinterpret_cast<const float4*>(xin + (size_t)n * HID + 4 * q);
    }
    __syncthreads();

    // U1: h[4q..4q+3] = relu(m@Wl + bl + xv@Wr)
    if (n < N_NODES) {
        float h4[4];
#pragma unroll
        for (int jj = 0; jj < 4; ++jj) {
            int j = 4 * q + jj;
            float a = sbl[j];
#pragma unroll
            for (int k = 0; k < HID; ++k)
                a += sacc[g * SACCP + k] * sWl[k * HID + j]
                   + sxv[g * SACCP + k] * sWr[k * HID + j];
            h4[jj] = fmaxf(a, 0.0f);
        }
        *reinterpret_cast<float4*>(&sh[g * SACCP + 4 * q]) =
            make_float4(h4[0], h4[1], h4[2], h4[3]);
    }
    __syncthreads();

    // U2: o[4q..4q+3] = h@Wlin + blin  -> coalesced store
    if (n < N_NODES) {
        float o4[4];
#pragma unroll
        for (int jj = 0; jj < 4; ++jj) {
            int j = 4 * q + jj;
            float a = sblin[j];
#pragma unroll
            for (int k = 0; k < HID; ++k) a += sh[g * SACCP + k] * sWlin[k * HID + j];
            o4[jj] = a;
        }
        *reinterpret_cast<float4*>(xout + (size_t)n * HID + 4 * q) =
            make_float4(o4[0], o4[1], o4[2], o4[3]);
    }
}

// ===========================================================================
// FALLBACK path (round-1, proven <=39.2MB): global-atomic scatter kernels
// ===========================================================================
__global__ void scatter0_kernel(const float* __restrict__ x,
                                const int* __restrict__ src,
                                const int* __restrict__ dst,
                                float* __restrict__ sum0,
                                float* __restrict__ deg) {
    int stride = gridDim.x * blockDim.x;
    for (int e = blockIdx.x * blockDim.x + threadIdx.x; e < N_EDGES; e += stride) {
        atomicAdd(&sum0[dst[e]], x[src[e]]);
        atomicAdd(&deg[dst[e]], 1.0f);
    }
}

__global__ void scatter16_kernel(const float* __restrict__ x,
                                 const int* __restrict__ src,
                                 const int* __restrict__ dst,
                                 float* __restrict__ summed) {
    int stride = gridDim.x * blockDim.x;
    const int total = N_EDGES * HID;
    for (int t = blockIdx.x * blockDim.x + threadIdx.x; t < total; t += stride) {
        int e = t >> 4, j = t & 15;
        atomicAdd(&summed[dst[e] * HID + j], x[src[e] * HID + j]);
    }
}

__global__ void node16_kernel(const float* __restrict__ xin,
                              const float* __restrict__ sums,
                              const float* __restrict__ deg,
                              const float* __restrict__ Wl, const float* __restrict__ bl,
                              const float* __restrict__ Wr,
                              const float* __restrict__ Wlin, const float* __restrict__ blin,
                              float* __restrict__ xout) {
    __shared__ float sWl[HID * HID], sWr[HID * HID], sWlin[HID * HID];
    __shared__ float sbl[HID], sblin[HID];
    if (threadIdx.x < HID * HID) {
        sWl[threadIdx.x] = Wl[threadIdx.x]; sWr[threadIdx.x] = Wr[threadIdx.x];
        sWlin[threadIdx.x] = Wlin[threadIdx.x];
    }
    if (threadIdx.x < HID) { sbl[threadIdx.x] = bl[threadIdx.x]; sblin[threadIdx.x] = blin[threadIdx.x]; }
    __syncthreads();
    int stride = gridDim.x * blockDim.x;
    for (int n = blockIdx.x * blockDim.x + threadIdx.x; n < N_NODES; n += stride) {
        float invd = 1.0f / fmaxf(deg[n], 1.0f);
        float m[HID], xv[HID];
        const float4* sp = reinterpret_cast<const float4*>(sums + (size_t)n * HID);
        const float4* xp = reinterpret_cast<const float4*>(xin + (size_t)n * HID);
#pragma unroll
        for (int qq = 0; qq < 4; ++qq) {
            float4 sv = sp[qq]; float4 vv = xp[qq];
            m[qq * 4 + 0] = sv.x * invd; m[qq * 4 + 1] = sv.y * invd;
            m[qq * 4 + 2] = sv.z * invd; m[qq * 4 + 3] = sv.w * invd;
            xv[qq * 4 + 0] = vv.x; xv[qq * 4 + 1] = vv.y; xv[qq * 4 + 2] = vv.z; xv[qq * 4 + 3] = vv.w;
        }
        float h[HID];
#pragma unroll
        for (int j = 0; j < HID; ++j) {
            float a = sbl[j];
#pragma unroll
            for (int k = 0; k < HID; ++k) a += m[k] * sWl[k * HID + j];
#pragma unroll
            for (int k = 0; k < HID; ++k) a += xv[k] * sWr[k * HID + j];
            h[j] = fmaxf(a, 0.0f);
        }
        float o[HID];
#pragma unroll
        for (int j = 0; j < HID; ++j) {
            float a = sblin[j];
#pragma unroll
            for (int k = 0; k < HID; ++k) a += h[k] * sWlin[k * HID + j];
            o[j] = a;
        }
        float4* op = reinterpret_cast<float4*>(xout + (size_t)n * HID);
#pragma unroll
        for (int qq = 0; qq < 4; ++qq)
            op[qq] = make_float4(o[qq * 4 + 0], o[qq * 4 + 1], o[qq * 4 + 2], o[qq * 4 + 3]);
    }
}

// ===========================================================================
// Attention pool + MLP head (batch sorted -> binary-searched range per graph)
// ===========================================================================
__global__ void pool_head_kernel(const float* __restrict__ x,
                                 const int* __restrict__ batch,
                                 const float* __restrict__ Wo0, const float* __restrict__ bo0,
                                 const float* __restrict__ Wo1, const float* __restrict__ bo1,
                                 const float* __restrict__ Wo2, const float* __restrict__ bo2,
                                 float* __restrict__ out) {
    int g = blockIdx.x;
    __shared__ int sRange[2];
    __shared__ float red_d[256], red_n[256];
    __shared__ float pooled[HID], h0[HID], h1[HID];

    if (threadIdx.x == 0) {
        int lo = 0, hi = N_NODES;
        while (lo < hi) { int mid = (lo + hi) >> 1; if (batch[mid] < g) lo = mid + 1; else hi = mid; }
        sRange[0] = lo;
        hi = N_NODES;
        while (lo < hi) { int mid = (lo + hi) >> 1; if (batch[mid] < g + 1) lo = mid + 1; else hi = mid; }
        sRange[1] = lo;
    }
    __syncthreads();
    int start = sRange[0], end = sRange[1];
    int j = threadIdx.x & 15;
    int sub = threadIdx.x >> 4;

    float dacc = 0.0f, nacc = 0.0f;
    for (int n = start + sub; n < end; n += 16) {
        float v = x[n * HID + j];
        float s = expf(ALPHA * v);
        dacc += s;
        nacc += s * v;
    }
    red_d[threadIdx.x] = dacc;
    red_n[threadIdx.x] = nacc;
    __syncthreads();

    if (threadIdx.x < HID) {
        float ds = 0.0f, ns = 0.0f;
        for (int k = 0; k < 16; ++k) {
            ds += red_d[k * 16 + threadIdx.x];
            ns += red_n[k * 16 + threadIdx.x];
        }
        pooled[threadIdx.x] = ds > 0.0f ? ns / ds : 0.0f;
    }
    __syncthreads();
    if (threadIdx.x < HID) {
        float acc = bo0[threadIdx.x];
        for (int k = 0; k < HID; ++k) acc += pooled[k] * Wo0[k * HID + threadIdx.x];
        h0[threadIdx.x] = fmaxf(acc, 0.0f);
    }
    __syncthreads();
    if (threadIdx.x < HID) {
        float acc = bo1[threadIdx.x];
        for (int k = 0; k < HID; ++k) acc += h0[k] * Wo1[k * HID + threadIdx.x];
        h1[threadIdx.x] = fmaxf(acc, 0.0f);
    }
    __syncthreads();
    if (threadIdx.x == 0) {
        float acc = bo2[0];
        for (int k = 0; k < HID; ++k) acc += h1[k] * Wo2[k];
        out[g] = acc;
    }
}

extern "C" void kernel_launch(void* const* d_in, const int* in_sizes, int n_in,
                              void* d_out, int out_size, void* d_ws, size_t ws_size,
                              hipStream_t stream) {
    const float* x      = (const float*)d_in[0];
    const int*   edge   = (const int*)d_in[1];
    const int*   batch  = (const int*)d_in[2];
    const float* Wl0    = (const float*)d_in[3];
    const float* bl0    = (const float*)d_in[4];
    const float* Wr0    = (const float*)d_in[5];
    const float* Wlin0  = (const float*)d_in[6];
    const float* blin0  = (const float*)d_in[7];
    const float* Wl1    = (const float*)d_in[8];
    const float* bl1    = (const float*)d_in[9];
    const float* Wr1    = (const float*)d_in[10];
    const float* Wlin1  = (const float*)d_in[11];
    const float* blin1  = (const float*)d_in[12];
    const float* Wl2    = (const float*)d_in[13];
    const float* bl2    = (const float*)d_in[14];
    const float* Wr2    = (const float*)d_in[15];
    const float* Wlin2  = (const float*)d_in[16];
    const float* blin2  = (const float*)d_in[17];
    const float* Wo0    = (const float*)d_in[18];
    const float* bo0    = (const float*)d_in[19];
    const float* Wo1    = (const float*)d_in[20];
    const float* bo1    = (const float*)d_in[21];
    const float* Wo2    = (const float*)d_in[22];
    const float* bo2    = (const float*)d_in[23];

    const int* src = edge;
    const int* dst = edge + N_EDGES;

    // ---- Workspace layout (main path), peak 48,000,528 B (unchanged) ----
    // persistent: sorted_src[5M] | row_ptr[N+1] | M-region | xa[N*16] | xb[N*16]
    // M-region (1,600,512 B) is reused: M[] during build, then sum0[N]+deg[N]
    // build-time aliases inside xa/xb region: packed[5M] | ct | bb
    const size_t OFF_SORTED = 0;                                   // 20,000,000
    const size_t OFF_ROW    = 20000000;                            //    800,016
    const size_t OFF_M      = 20800016;                            //  1,600,512
    const size_t OFF_XA     = 22400528;                            // 12,800,000
    const size_t OFF_XB     = 35200528;                            // 12,800,000
    const size_t NEED_MAIN  = 48000528;
    const size_t OFF_PACKED = OFF_XA;                              // dies before xa written
    const size_t OFF_CT     = 42400528;                            // inside xb, dies before xb written
    const size_t OFF_BB     = 42406800;

    char* ws = (char*)d_ws;

    if (ws_size >= NEED_MAIN) {
        int*   sorted_src  = (int*)(ws + OFF_SORTED);
        int*   row_ptr     = (int*)(ws + OFF_ROW);
        int*   M           = (int*)(ws + OFF_M);
        float* sum0        = (float*)(ws + OFF_M);                 // reuse after build
        float* degf        = sum0 + N_NODES;
        float* xa          = (float*)(ws + OFF_XA);
        float* xb          = (float*)(ws + OFF_XB);
        int*   packed      = (int*)(ws + OFF_PACKED);
        int*   col_total   = (int*)(ws + OFF_CT);
        int*   bucket_base = (int*)(ws + OFF_BB);

        // Build: bucket sort -> per-bucket CSR finish (+ fused d=1 aggregation)
        count_kernel<<<NWGB, 256, 0, stream>>>(dst, M);
        colscan_kernel<<<(NB + 255) / 256, 256, 0, stream>>>(M, col_total);
        bucketscan_kernel<<<1, 256, 0, stream>>>(col_total, bucket_base);
        scatter_build_kernel<<<NWGB, 256, 0, stream>>>(src, dst, M, bucket_base, packed);
        csr_kernel<<<NB, 256, 0, stream>>>(x, packed, bucket_base, row_ptr, sorted_src,
                                           sum0, degf);

        // Layer 0 node update (streaming)
        node0_kernel<<<784, 256, 0, stream>>>(x, sum0, degf, Wl0, bl0, Wr0, Wlin0, blin0, xa);
        // Layers 1/2
        layerB_csr<<<(N_NODES + 63) / 64, 256, 0, stream>>>(
            xa, row_ptr, sorted_src, Wl1, bl1, Wr1, Wlin1, blin1, xb);
        layerB_csr<<<(N_NODES + 63) / 64, 256, 0, stream>>>(
            xb, row_ptr, sorted_src, Wl2, bl2, Wr2, Wlin2, blin2, xa);

        pool_head_kernel<<<N_GRAPHS, 256, 0, stream>>>(xa, batch, Wo0, bo0, Wo1, bo1,
                                                       Wo2, bo2, (float*)d_out);
    } else {
        // ---- Fallback (round-1, proven 39.2 MB): global-atomic scatter ----
        float* deg    = (float*)ws;
        float* summed = deg + N_NODES;
        float* xa     = summed + (size_t)N_NODES * HID;
        float* xb     = xa + (size_t)N_NODES * HID;

        hipMemsetAsync(deg, 0, sizeof(float) * (size_t)N_NODES * (1 + HID), stream);
        scatter0_kernel<<<2048, 256, 0, stream>>>(x, src, dst, summed, deg);
        node0_kernel<<<784, 256, 0, stream>>>(x, summed, deg, Wl0, bl0, Wr0, Wlin0, blin0, xa);

        hipMemsetAsync(summed, 0, sizeof(float) * (size_t)N_NODES * HID, stream);
        scatter16_kernel<<<4096, 256, 0, stream>>>(xa, src, dst, summed);
        node16_kernel<<<784, 256, 0, stream>>>(xa, summed, deg, Wl1, bl1, Wr1, Wlin1, blin1, xb);

        hipMemsetAsync(summed, 0, sizeof(float) * (size_t)N_NODES * HID, stream);
        scatter16_kernel<<<4096, 256, 0, stream>>>(xb, src, dst, summed);
        node16_kernel<<<784, 256, 0, stream>>>(xb, summed, deg, Wl2, bl2, Wr2, Wlin2, blin2, xa);

        pool_head_kernel<<<N_GRAPHS, 256, 0, stream>>>(xa, batch, Wo0, bo0, Wo1, bo1,
                                                       Wo2, bo2, (float*)d_out);
    }
}

// Round 10
// 501.129 us; speedup vs baseline: 1.3024x; 1.3024x over previous
//
#include <hip/hip_runtime.h>

#define N_NODES 200000
#define N_EDGES 5000000
#define N_GRAPHS 1024
#define HID 16
#define ALPHA 0.2f

#define BSH 7
#define BSZ 128                      // nodes per bucket
#define NB 1563                      // ceil(N_NODES / BSZ)
#define NWGB 256                     // build workgroups (M columns)
#define EPB ((N_EDGES + NWGB - 1) / NWGB)  // 19532 (divisible by 4)

#define SACCP 20                     // LDS stride (floats) for staging

// ===========================================================================
// BUILD stage 1: counting sort of edges by dst >> 7 into packed (src<<7|dl)
// M layout WG-major: M[w * NB + b] (coalesced). 1024 threads/block for
// occupancy (4x waves vs 256).
// ===========================================================================
__global__ void count_kernel(const int* __restrict__ dst, int* __restrict__ M) {
    __shared__ int hist[NB];
    for (int i = threadIdx.x; i < NB; i += 1024) hist[i] = 0;
    __syncthreads();
    int base = blockIdx.x * EPB;
    int end = min(base + EPB, N_EDGES);
    for (int e = base + threadIdx.x * 4; e < end; e += 1024 * 4) {
        int4 d4 = *reinterpret_cast<const int4*>(dst + e);
        atomicAdd(&hist[d4.x >> BSH], 1);
        atomicAdd(&hist[d4.y >> BSH], 1);
        atomicAdd(&hist[d4.z >> BSH], 1);
        atomicAdd(&hist[d4.w >> BSH], 1);
    }
    __syncthreads();
    for (int i = threadIdx.x; i < NB; i += 1024)
        M[blockIdx.x * NB + i] = hist[i];
}

__global__ void colscan_kernel(int* __restrict__ M, int* __restrict__ col_total) {
    int b = blockIdx.x * blockDim.x + threadIdx.x;
    if (b >= NB) return;
    int run = 0;
#pragma unroll 8
    for (int w = 0; w < NWGB; ++w) {
        int v = M[w * NB + b];      // coalesced across threads
        M[w * NB + b] = run;
        run += v;
    }
    col_total[b] = run;
}

__global__ void bucketscan_kernel(const int* __restrict__ col_total,
                                  int* __restrict__ bucket_base) {
    __shared__ int sc[256];
    int t = threadIdx.x;
    int v[7];
    int s = 0;
#pragma unroll
    for (int k = 0; k < 7; ++k) {
        int i = t * 7 + k;
        v[k] = (i < NB) ? col_total[i] : 0;
        s += v[k];
    }
    sc[t] = s;
    __syncthreads();
    for (int off = 1; off < 256; off <<= 1) {
        int tmp = (t >= off) ? sc[t - off] : 0;
        __syncthreads();
        sc[t] += tmp;
        __syncthreads();
    }
    int excl = sc[t] - s;
#pragma unroll
    for (int k = 0; k < 7; ++k) {
        int i = t * 7 + k;
        if (i < NB) bucket_base[i] = excl;
        excl += v[k];
    }
    if (t == 255) bucket_base[NB] = sc[255];
}

__global__ void scatter_build_kernel(const int* __restrict__ src,
                                     const int* __restrict__ dst,
                                     const int* __restrict__ M,
                                     const int* __restrict__ bucket_base,
                                     int* __restrict__ packed) {
    __shared__ int cur[NB];
    int w = blockIdx.x;
    for (int i = threadIdx.x; i < NB; i += 1024)
        cur[i] = bucket_base[i] + M[w * NB + i];
    __syncthreads();
    int base = w * EPB;
    int end = min(base + EPB, N_EDGES);
    for (int e = base + threadIdx.x * 4; e < end; e += 1024 * 4) {
        int4 s4 = *reinterpret_cast<const int4*>(src + e);
        int4 d4 = *reinterpret_cast<const int4*>(dst + e);
        int p;
        p = atomicAdd(&cur[d4.x >> BSH], 1); packed[p] = (s4.x << BSH) | (d4.x & (BSZ - 1));
        p = atomicAdd(&cur[d4.y >> BSH], 1); packed[p] = (s4.y << BSH) | (d4.y & (BSZ - 1));
        p = atomicAdd(&cur[d4.z >> BSH], 1); packed[p] = (s4.z << BSH) | (d4.z & (BSZ - 1));
        p = atomicAdd(&cur[d4.w >> BSH], 1); packed[p] = (s4.w << BSH) | (d4.w & (BSZ - 1));
    }
}

// ===========================================================================
// BUILD stage 2: per-bucket count/scan/scatter -> CSR (row_ptr, sorted_src)
// ===========================================================================
__global__ void csr_kernel(const int* __restrict__ packed,
                           const int* __restrict__ bucket_base,
                           int* __restrict__ row_ptr,
                           int* __restrict__ sorted_src) {
    __shared__ int cnt[BSZ], scn[BSZ], cur[BSZ];
    int t = threadIdx.x, b = blockIdx.x;
    if (t < BSZ) cnt[t] = 0;
    __syncthreads();
    int e0 = bucket_base[b], e1 = bucket_base[b + 1];
    for (int i = e0 + t; i < e1; i += 256)
        atomicAdd(&cnt[packed[i] & (BSZ - 1)], 1);
    __syncthreads();
    if (t < BSZ) scn[t] = cnt[t];
    __syncthreads();
    for (int off = 1; off < BSZ; off <<= 1) {
        int v = 0;
        if (t < BSZ && t >= off) v = scn[t - off];
        __syncthreads();
        if (t < BSZ) scn[t] += v;
        __syncthreads();
    }
    if (t < BSZ) {
        int node = b * BSZ + t;
        int base = e0 + scn[t] - cnt[t];   // exclusive scan
        if (node < N_NODES) row_ptr[node] = base;
        cur[t] = base;
    }
    if (b == NB - 1 && t == 0) row_ptr[N_NODES] = N_EDGES;
    __syncthreads();
    for (int i = e0 + t; i < e1; i += 256) {
        int pk = packed[i];
        int p = atomicAdd(&cur[pk & (BSZ - 1)], 1);
        sorted_src[p] = pk >> BSH;
    }
}

// ===========================================================================
// Layer 0 (d=1): CSR register aggregation + fused node update. 1 thread/node.
// ===========================================================================
__global__ void layer0_csr(const float* __restrict__ x,
                           const int* __restrict__ row_ptr,
                           const int* __restrict__ sorted_src,
                           const float* __restrict__ Wl, const float* __restrict__ bl,
                           const float* __restrict__ Wr,
                           const float* __restrict__ Wlin, const float* __restrict__ blin,
                           float* __restrict__ xout) {
    __shared__ float sWl[HID], sWr[HID], sbl[HID], sblin[HID], sWlin[HID * HID];
    int t = threadIdx.x;
    if (t < HID) {
        sWl[t] = Wl[t]; sWr[t] = Wr[t]; sbl[t] = bl[t]; sblin[t] = blin[t];
    }
    if (t < HID * HID) sWlin[t] = Wlin[t];
    __syncthreads();

    int n = blockIdx.x * 256 + t;
    if (n >= N_NODES) return;
    int r0 = row_ptr[n], r1 = row_ptr[n + 1];
    float sum = 0.0f;
    int i = r0;
    for (; i + 4 <= r1; i += 4) {
        int s0 = sorted_src[i], s1 = sorted_src[i + 1];
        int s2 = sorted_src[i + 2], s3 = sorted_src[i + 3];
        sum += x[s0] + x[s1] + x[s2] + x[s3];
    }
    for (; i < r1; ++i) sum += x[sorted_src[i]];
    float mean = sum / fmaxf((float)(r1 - r0), 1.0f);
    float xv = x[n];
    float h[HID];
#pragma unroll
    for (int j = 0; j < HID; ++j)
        h[j] = fmaxf(mean * sWl[j] + sbl[j] + xv * sWr[j], 0.0f);
    float o[HID];
#pragma unroll
    for (int j = 0; j < HID; ++j) {
        float a = sblin[j];
#pragma unroll
        for (int k = 0; k < HID; ++k) a += h[k] * sWlin[k * HID + j];
        o[j] = a;
    }
    float4* op = reinterpret_cast<float4*>(xout + (size_t)n * HID);
#pragma unroll
    for (int q = 0; q < 4; ++q)
        op[q] = make_float4(o[q * 4 + 0], o[q * 4 + 1], o[q * 4 + 2], o[q * 4 + 3]);
}

// ===========================================================================
// Layers 1/2 (d=16): 4-lane group per node, float4 register accumulation,
// 8 independent cache-line gathers in flight per group per iteration.
// Fused node update via LDS staging. 64 nodes per 256-thread block.
// ===========================================================================
__global__ void layerB_csr(const float* __restrict__ xin,
                           const int* __restrict__ row_ptr,
                           const int* __restrict__ sorted_src,
                           const float* __restrict__ Wl, const float* __restrict__ bl,
                           const float* __restrict__ Wr,
                           const float* __restrict__ Wlin, const float* __restrict__ blin,
                           float* __restrict__ xout) {
    __shared__ float sacc[64 * SACCP];
    __shared__ float sxv[64 * SACCP];
    __shared__ float sh[64 * SACCP];
    __shared__ float sWl[HID * HID], sWr[HID * HID], sWlin[HID * HID];
    __shared__ float sbl[HID], sblin[HID];
    int t = threadIdx.x;
    if (t < HID * HID) { sWl[t] = Wl[t]; sWr[t] = Wr[t]; sWlin[t] = Wlin[t]; }
    if (t < HID) { sbl[t] = bl[t]; sblin[t] = blin[t]; }
    __syncthreads();

    int q = t & 3;           // feature quad: features 4q..4q+3
    int g = t >> 2;          // group 0..63 -> node
    int n = blockIdx.x * 64 + g;

    if (n < N_NODES) {
        int r0 = row_ptr[n], r1 = row_ptr[n + 1];
        const float* xq = xin + 4 * q;
        float4 acc = make_float4(0.0f, 0.0f, 0.0f, 0.0f);
        int i = r0;
        for (; i + 8 <= r1; i += 8) {
            int s0 = sorted_src[i],     s1 = sorted_src[i + 1];
            int s2 = sorted_src[i + 2], s3 = sorted_src[i + 3];
            int s4 = sorted_src[i + 4], s5 = sorted_src[i + 5];
            int s6 = sorted_src[i + 6], s7 = sorted_src[i + 7];
            float4 g0 = *reinterpret_cast<const float4*>(xq + (size_t)s0 * HID);
            float4 g1 = *reinterpret_cast<const float4*>(xq + (size_t)s1 * HID);
            float4 g2 = *reinterpret_cast<const float4*>(xq + (size_t)s2 * HID);
            float4 g3 = *reinterpret_cast<const float4*>(xq + (size_t)s3 * HID);
            float4 g4 = *reinterpret_cast<const float4*>(xq + (size_t)s4 * HID);
            float4 g5 = *reinterpret_cast<const float4*>(xq + (size_t)s5 * HID);
            float4 g6 = *reinterpret_cast<const float4*>(xq + (size_t)s6 * HID);
            float4 g7 = *reinterpret_cast<const float4*>(xq + (size_t)s7 * HID);
            acc.x += (g0.x + g1.x + g2.x + g3.x) + (g4.x + g5.x + g6.x + g7.x);
            acc.y += (g0.y + g1.y + g2.y + g3.y) + (g4.y + g5.y + g6.y + g7.y);
            acc.z += (g0.z + g1.z + g2.z + g3.z) + (g4.z + g5.z + g6.z + g7.z);
            acc.w += (g0.w + g1.w + g2.w + g3.w) + (g4.w + g5.w + g6.w + g7.w);
        }
        for (; i + 4 <= r1; i += 4) {
            int s0 = sorted_src[i],     s1 = sorted_src[i + 1];
            int s2 = sorted_src[i + 2], s3 = sorted_src[i + 3];
            float4 g0 = *reinterpret_cast<const float4*>(xq + (size_t)s0 * HID);
            float4 g1 = *reinterpret_cast<const float4*>(xq + (size_t)s1 * HID);
            float4 g2 = *reinterpret_cast<const float4*>(xq + (size_t)s2 * HID);
            float4 g3 = *reinterpret_cast<const float4*>(xq + (size_t)s3 * HID);
            acc.x += g0.x + g1.x + g2.x + g3.x;
            acc.y += g0.y + g1.y + g2.y + g3.y;
            acc.z += g0.z + g1.z + g2.z + g3.z;
            acc.w += g0.w + g1.w + g2.w + g3.w;
        }
        for (; i < r1; ++i) {
            float4 gv = *reinterpret_cast<const float4*>(xq + (size_t)sorted_src[i] * HID);
            acc.x += gv.x; acc.y += gv.y; acc.z += gv.z; acc.w += gv.w;
        }
        float invd = 1.0f / fmaxf((float)(r1 - r0), 1.0f);
        acc.x *= invd; acc.y *= invd; acc.z *= invd; acc.w *= invd;
        *reinterpret_cast<float4*>(&sacc[g * SACCP + 4 * q]) = acc;
        *reinterpret_cast<float4*>(&sxv[g * SACCP + 4 * q]) =
            *reinterpret_cast<const float4*>(xin + (size_t)n * HID + 4 * q);
    }
    __syncthreads();

    // U1: h[4q..4q+3] = relu(m@Wl + bl + xv@Wr)
    if (n < N_NODES) {
        float h4[4];
#pragma unroll
        for (int jj = 0; jj < 4; ++jj) {
            int j = 4 * q + jj;
            float a = sbl[j];
#pragma unroll
            for (int k = 0; k < HID; ++k)
                a += sacc[g * SACCP + k] * sWl[k * HID + j]
                   + sxv[g * SACCP + k] * sWr[k * HID + j];
            h4[jj] = fmaxf(a, 0.0f);
        }
        *reinterpret_cast<float4*>(&sh[g * SACCP + 4 * q]) =
            make_float4(h4[0], h4[1], h4[2], h4[3]);
    }
    __syncthreads();

    // U2: o[4q..4q+3] = h@Wlin + blin  -> coalesced store
    if (n < N_NODES) {
        float o4[4];
#pragma unroll
        for (int jj = 0; jj < 4; ++jj) {
            int j = 4 * q + jj;
            float a = sblin[j];
#pragma unroll
            for (int k = 0; k < HID; ++k) a += sh[g * SACCP + k] * sWlin[k * HID + j];
            o4[jj] = a;
        }
        *reinterpret_cast<float4*>(xout + (size_t)n * HID + 4 * q) =
            make_float4(o4[0], o4[1], o4[2], o4[3]);
    }
}

// ===========================================================================
// FALLBACK path (round-1, proven <=39.2MB): global-atomic scatter kernels
// ===========================================================================
__global__ void scatter0_kernel(const float* __restrict__ x,
                                const int* __restrict__ src,
                                const int* __restrict__ dst,
                                float* __restrict__ sum0,
                                float* __restrict__ deg) {
    int stride = gridDim.x * blockDim.x;
    for (int e = blockIdx.x * blockDim.x + threadIdx.x; e < N_EDGES; e += stride) {
        atomicAdd(&sum0[dst[e]], x[src[e]]);
        atomicAdd(&deg[dst[e]], 1.0f);
    }
}

__global__ void scatter16_kernel(const float* __restrict__ x,
                                 const int* __restrict__ src,
                                 const int* __restrict__ dst,
                                 float* __restrict__ summed) {
    int stride = gridDim.x * blockDim.x;
    const int total = N_EDGES * HID;
    for (int t = blockIdx.x * blockDim.x + threadIdx.x; t < total; t += stride) {
        int e = t >> 4, j = t & 15;
        atomicAdd(&summed[dst[e] * HID + j], x[src[e] * HID + j]);
    }
}

__global__ void node0_kernel(const float* __restrict__ x,
                             const float* __restrict__ sum0,
                             const float* __restrict__ deg,
                             const float* __restrict__ Wl, const float* __restrict__ bl,
                             const float* __restrict__ Wr,
                             const float* __restrict__ Wlin, const float* __restrict__ blin,
                             float* __restrict__ xout) {
    __shared__ float sWl[HID], sWr[HID], sbl[HID], sblin[HID], sWlin[HID * HID];
    if (threadIdx.x < HID) {
        sWl[threadIdx.x] = Wl[threadIdx.x]; sWr[threadIdx.x] = Wr[threadIdx.x];
        sbl[threadIdx.x] = bl[threadIdx.x]; sblin[threadIdx.x] = blin[threadIdx.x];
    }
    if (threadIdx.x < HID * HID) sWlin[threadIdx.x] = Wlin[threadIdx.x];
    __syncthreads();
    int stride = gridDim.x * blockDim.x;
    for (int n = blockIdx.x * blockDim.x + threadIdx.x; n < N_NODES; n += stride) {
        float mean = sum0[n] / fmaxf(deg[n], 1.0f);
        float xv = x[n];
        float h[HID];
#pragma unroll
        for (int j = 0; j < HID; ++j)
            h[j] = fmaxf(mean * sWl[j] + sbl[j] + xv * sWr[j], 0.0f);
#pragma unroll
        for (int j = 0; j < HID; ++j) {
            float acc = sblin[j];
#pragma unroll
            for (int k = 0; k < HID; ++k) acc += h[k] * sWlin[k * HID + j];
            xout[n * HID + j] = acc;
        }
    }
}

__global__ void node16_kernel(const float* __restrict__ xin,
                              const float* __restrict__ sums,
                              const float* __restrict__ deg,
                              const float* __restrict__ Wl, const float* __restrict__ bl,
                              const float* __restrict__ Wr,
                              const float* __restrict__ Wlin, const float* __restrict__ blin,
                              float* __restrict__ xout) {
    __shared__ float sWl[HID * HID], sWr[HID * HID], sWlin[HID * HID];
    __shared__ float sbl[HID], sblin[HID];
    if (threadIdx.x < HID * HID) {
        sWl[threadIdx.x] = Wl[threadIdx.x]; sWr[threadIdx.x] = Wr[threadIdx.x];
        sWlin[threadIdx.x] = Wlin[threadIdx.x];
    }
    if (threadIdx.x < HID) { sbl[threadIdx.x] = bl[threadIdx.x]; sblin[threadIdx.x] = blin[threadIdx.x]; }
    __syncthreads();
    int stride = gridDim.x * blockDim.x;
    for (int n = blockIdx.x * blockDim.x + threadIdx.x; n < N_NODES; n += stride) {
        float invd = 1.0f / fmaxf(deg[n], 1.0f);
        float m[HID], xv[HID];
        const float4* sp = reinterpret_cast<const float4*>(sums + (size_t)n * HID);
        const float4* xp = reinterpret_cast<const float4*>(xin + (size_t)n * HID);
#pragma unroll
        for (int qq = 0; qq < 4; ++qq) {
            float4 sv = sp[qq]; float4 vv = xp[qq];
            m[qq * 4 + 0] = sv.x * invd; m[qq * 4 + 1] = sv.y * invd;
            m[qq * 4 + 2] = sv.z * invd; m[qq * 4 + 3] = sv.w * invd;
            xv[qq * 4 + 0] = vv.x; xv[qq * 4 + 1] = vv.y; xv[qq * 4 + 2] = vv.z; xv[qq * 4 + 3] = vv.w;
        }
        float h[HID];
#pragma unroll
        for (int j = 0; j < HID; ++j) {
            float a = sbl[j];
#pragma unroll
            for (int k = 0; k < HID; ++k) a += m[k] * sWl[k * HID + j];
#pragma unroll
            for (int k = 0; k < HID; ++k) a += xv[k] * sWr[k * HID + j];
            h[j] = fmaxf(a, 0.0f);
        }
        float o[HID];
#pragma unroll
        for (int j = 0; j < HID; ++j) {
            float a = sblin[j];
#pragma unroll
            for (int k = 0; k < HID; ++k) a += h[k] * sWlin[k * HID + j];
            o[j] = a;
        }
        float4* op = reinterpret_cast<float4*>(xout + (size_t)n * HID);
#pragma unroll
        for (int qq = 0; qq < 4; ++qq)
            op[qq] = make_float4(o[qq * 4 + 0], o[qq * 4 + 1], o[qq * 4 + 2], o[qq * 4 + 3]);
    }
}

// ===========================================================================
// Attention pool + MLP head (batch sorted -> binary-searched range per graph)
// ===========================================================================
__global__ void pool_head_kernel(const float* __restrict__ x,
                                 const int* __restrict__ batch,
                                 const float* __restrict__ Wo0, const float* __restrict__ bo0,
                                 const float* __restrict__ Wo1, const float* __restrict__ bo1,
                                 const float* __restrict__ Wo2, const float* __restrict__ bo2,
                                 float* __restrict__ out) {
    int g = blockIdx.x;
    __shared__ int sRange[2];
    __shared__ float red_d[256], red_n[256];
    __shared__ float pooled[HID], h0[HID], h1[HID];

    if (threadIdx.x == 0) {
        int lo = 0, hi = N_NODES;
        while (lo < hi) { int mid = (lo + hi) >> 1; if (batch[mid] < g) lo = mid + 1; else hi = mid; }
        sRange[0] = lo;
        hi = N_NODES;
        while (lo < hi) { int mid = (lo + hi) >> 1; if (batch[mid] < g + 1) lo = mid + 1; else hi = mid; }
        sRange[1] = lo;
    }
    __syncthreads();
    int start = sRange[0], end = sRange[1];
    int j = threadIdx.x & 15;
    int sub = threadIdx.x >> 4;

    float dacc = 0.0f, nacc = 0.0f;
    for (int n = start + sub; n < end; n += 16) {
        float v = x[n * HID + j];
        float s = expf(ALPHA * v);
        dacc += s;
        nacc += s * v;
    }
    red_d[threadIdx.x] = dacc;
    red_n[threadIdx.x] = nacc;
    __syncthreads();

    if (threadIdx.x < HID) {
        float ds = 0.0f, ns = 0.0f;
        for (int k = 0; k < 16; ++k) {
            ds += red_d[k * 16 + threadIdx.x];
            ns += red_n[k * 16 + threadIdx.x];
        }
        pooled[threadIdx.x] = ds > 0.0f ? ns / ds : 0.0f;
    }
    __syncthreads();
    if (threadIdx.x < HID) {
        float acc = bo0[threadIdx.x];
        for (int k = 0; k < HID; ++k) acc += pooled[k] * Wo0[k * HID + threadIdx.x];
        h0[threadIdx.x] = fmaxf(acc, 0.0f);
    }
    __syncthreads();
    if (threadIdx.x < HID) {
        float acc = bo1[threadIdx.x];
        for (int k = 0; k < HID; ++k) acc += h0[k] * Wo1[k * HID + threadIdx.x];
        h1[threadIdx.x] = fmaxf(acc, 0.0f);
    }
    __syncthreads();
    if (threadIdx.x == 0) {
        float acc = bo2[0];
        for (int k = 0; k < HID; ++k) acc += h1[k] * Wo2[k];
        out[g] = acc;
    }
}

extern "C" void kernel_launch(void* const* d_in, const int* in_sizes, int n_in,
                              void* d_out, int out_size, void* d_ws, size_t ws_size,
                              hipStream_t stream) {
    const float* x      = (const float*)d_in[0];
    const int*   edge   = (const int*)d_in[1];
    const int*   batch  = (const int*)d_in[2];
    const float* Wl0    = (const float*)d_in[3];
    const float* bl0    = (const float*)d_in[4];
    const float* Wr0    = (const float*)d_in[5];
    const float* Wlin0  = (const float*)d_in[6];
    const float* blin0  = (const float*)d_in[7];
    const float* Wl1    = (const float*)d_in[8];
    const float* bl1    = (const float*)d_in[9];
    const float* Wr1    = (const float*)d_in[10];
    const float* Wlin1  = (const float*)d_in[11];
    const float* blin1  = (const float*)d_in[12];
    const float* Wl2    = (const float*)d_in[13];
    const float* bl2    = (const float*)d_in[14];
    const float* Wr2    = (const float*)d_in[15];
    const float* Wlin2  = (const float*)d_in[16];
    const float* blin2  = (const float*)d_in[17];
    const float* Wo0    = (const float*)d_in[18];
    const float* bo0    = (const float*)d_in[19];
    const float* Wo1    = (const float*)d_in[20];
    const float* bo1    = (const float*)d_in[21];
    const float* Wo2    = (const float*)d_in[22];
    const float* bo2    = (const float*)d_in[23];

    const int* src = edge;
    const int* dst = edge + N_EDGES;

    // ---- Workspace layout (main path), peak 48,000,528 B (round-5 proven) ----
    // persistent: sorted_src[5M] | row_ptr[N+1] | M[NWGB*NB] | xa[N*16] | xb[N*16]
    // build-time aliases inside xa/xb region: packed[5M] | ct | bb
    const size_t OFF_SORTED = 0;                                   // 20,000,000
    const size_t OFF_ROW    = 20000000;                            //    800,016
    const size_t OFF_M      = 20800016;                            //  1,600,512
    const size_t OFF_XA     = 22400528;                            // 12,800,000
    const size_t OFF_XB     = 35200528;                            // 12,800,000
    const size_t NEED_MAIN  = 48000528;
    const size_t OFF_PACKED = OFF_XA;                              // dies before xa written
    const size_t OFF_CT     = 42400528;                            // inside xb, dies before xb written
    const size_t OFF_BB     = 42406800;

    char* ws = (char*)d_ws;

    if (ws_size >= NEED_MAIN) {
        int*   sorted_src  = (int*)(ws + OFF_SORTED);
        int*   row_ptr     = (int*)(ws + OFF_ROW);
        int*   M           = (int*)(ws + OFF_M);
        float* xa          = (float*)(ws + OFF_XA);
        float* xb          = (float*)(ws + OFF_XB);
        int*   packed      = (int*)(ws + OFF_PACKED);
        int*   col_total   = (int*)(ws + OFF_CT);
        int*   bucket_base = (int*)(ws + OFF_BB);

        // Build: bucket sort -> per-bucket CSR finish
        count_kernel<<<NWGB, 1024, 0, stream>>>(dst, M);
        colscan_kernel<<<(NB + 255) / 256, 256, 0, stream>>>(M, col_total);
        bucketscan_kernel<<<1, 256, 0, stream>>>(col_total, bucket_base);
        scatter_build_kernel<<<NWGB, 1024, 0, stream>>>(src, dst, M, bucket_base, packed);
        csr_kernel<<<NB, 256, 0, stream>>>(packed, bucket_base, row_ptr, sorted_src);

        // Layers (packed region now dead; xa/xb live)
        layer0_csr<<<(N_NODES + 255) / 256, 256, 0, stream>>>(
            x, row_ptr, sorted_src, Wl0, bl0, Wr0, Wlin0, blin0, xa);
        layerB_csr<<<(N_NODES + 63) / 64, 256, 0, stream>>>(
            xa, row_ptr, sorted_src, Wl1, bl1, Wr1, Wlin1, blin1, xb);
        layerB_csr<<<(N_NODES + 63) / 64, 256, 0, stream>>>(
            xb, row_ptr, sorted_src, Wl2, bl2, Wr2, Wlin2, blin2, xa);

        pool_head_kernel<<<N_GRAPHS, 256, 0, stream>>>(xa, batch, Wo0, bo0, Wo1, bo1,
                                                       Wo2, bo2, (float*)d_out);
    } else {
        // ---- Fallback (round-1, proven 39.2 MB): global-atomic scatter ----
        float* deg    = (float*)ws;
        float* summed = deg + N_NODES;
        float* xa     = summed + (size_t)N_NODES * HID;
        float* xb     = xa + (size_t)N_NODES * HID;

        hipMemsetAsync(deg, 0, sizeof(float) * (size_t)N_NODES * (1 + HID), stream);
        scatter0_kernel<<<2048, 256, 0, stream>>>(x, src, dst, summed, deg);
        node0_kernel<<<784, 256, 0, stream>>>(x, summed, deg, Wl0, bl0, Wr0, Wlin0, blin0, xa);

        hipMemsetAsync(summed, 0, sizeof(float) * (size_t)N_NODES * HID, stream);
        scatter16_kernel<<<4096, 256, 0, stream>>>(xa, src, dst, summed);
        node16_kernel<<<784, 256, 0, stream>>>(xa, summed, deg, Wl1, bl1, Wr1, Wlin1, blin1, xb);

        hipMemsetAsync(summed, 0, sizeof(float) * (size_t)N_NODES * HID, stream);
        scatter16_kernel<<<4096, 256, 0, stream>>>(xb, src, dst, summed);
        node16_kernel<<<784, 256, 0, stream>>>(xb, summed, deg, Wl2, bl2, Wr2, Wlin2, blin2, xa);

        pool_head_kernel<<<N_GRAPHS, 256, 0, stream>>>(xa, batch, Wo0, bo0, Wo1, bo1,
                                                       Wo2, bo2, (float*)d_out);
    }
}

// Round 13
// 476.428 us; speedup vs baseline: 1.3699x; 1.0518x over previous
//
#include <hip/hip_runtime.h>

#define N_NODES 200000
#define N_EDGES 5000000
#define N_GRAPHS 1024
#define HID 16
#define ALPHA 0.2f

#define BSH 7
#define BSZ 128                      // nodes per bucket
#define NB 1563                      // ceil(N_NODES / BSZ)
#define NWGB 256                     // build workgroups (M columns)
#define EPB ((N_EDGES + NWGB - 1) / NWGB)  // 19532 (divisible by 4)
#define ECAP 4096                    // LDS edge cache (bucket mean 3200, sd 57)

#define SACCP 20                     // LDS stride (floats) for staging

// ===========================================================================
// BUILD stage 1: counting sort of edges by dst >> 7 into packed (src<<7|dl)
// M layout WG-major: M[w * NB + b] (coalesced). 1024 threads/block.
// ===========================================================================
__global__ void count_kernel(const int* __restrict__ dst, int* __restrict__ M) {
    __shared__ int hist[NB];
    for (int i = threadIdx.x; i < NB; i += 1024) hist[i] = 0;
    __syncthreads();
    int base = blockIdx.x * EPB;
    int end = min(base + EPB, N_EDGES);
    for (int e = base + threadIdx.x * 4; e < end; e += 1024 * 4) {
        int4 d4 = *reinterpret_cast<const int4*>(dst + e);
        atomicAdd(&hist[d4.x >> BSH], 1);
        atomicAdd(&hist[d4.y >> BSH], 1);
        atomicAdd(&hist[d4.z >> BSH], 1);
        atomicAdd(&hist[d4.w >> BSH], 1);
    }
    __syncthreads();
    for (int i = threadIdx.x; i < NB; i += 1024)
        M[blockIdx.x * NB + i] = hist[i];
}

__global__ void colscan_kernel(int* __restrict__ M, int* __restrict__ col_total) {
    int b = blockIdx.x * blockDim.x + threadIdx.x;
    if (b >= NB) return;
    int run = 0;
#pragma unroll 8
    for (int w = 0; w < NWGB; ++w) {
        int v = M[w * NB + b];      // coalesced across threads
        M[w * NB + b] = run;
        run += v;
    }
    col_total[b] = run;
}

__global__ void bucketscan_kernel(const int* __restrict__ col_total,
                                  int* __restrict__ bucket_base) {
    __shared__ int sc[256];
    int t = threadIdx.x;
    int v[7];
    int s = 0;
#pragma unroll
    for (int k = 0; k < 7; ++k) {
        int i = t * 7 + k;
        v[k] = (i < NB) ? col_total[i] : 0;
        s += v[k];
    }
    sc[t] = s;
    __syncthreads();
    for (int off = 1; off < 256; off <<= 1) {
        int tmp = (t >= off) ? sc[t - off] : 0;
        __syncthreads();
        sc[t] += tmp;
        __syncthreads();
    }
    int excl = sc[t] - s;
#pragma unroll
    for (int k = 0; k < 7; ++k) {
        int i = t * 7 + k;
        if (i < NB) bucket_base[i] = excl;
        excl += v[k];
    }
    if (t == 255) bucket_base[NB] = sc[255];
}

__global__ void scatter_build_kernel(const int* __restrict__ src,
                                     const int* __restrict__ dst,
                                     const int* __restrict__ M,
                                     const int* __restrict__ bucket_base,
                                     int* __restrict__ packed) {
    __shared__ int cur[NB];
    int w = blockIdx.x;
    for (int i = threadIdx.x; i < NB; i += 1024)
        cur[i] = bucket_base[i] + M[w * NB + i];
    __syncthreads();
    int base = w * EPB;
    int end = min(base + EPB, N_EDGES);
    for (int e = base + threadIdx.x * 4; e < end; e += 1024 * 4) {
        int4 s4 = *reinterpret_cast<const int4*>(src + e);
        int4 d4 = *reinterpret_cast<const int4*>(dst + e);
        int p;
        p = atomicAdd(&cur[d4.x >> BSH], 1); packed[p] = (s4.x << BSH) | (d4.x & (BSZ - 1));
        p = atomicAdd(&cur[d4.y >> BSH], 1); packed[p] = (s4.y << BSH) | (d4.y & (BSZ - 1));
        p = atomicAdd(&cur[d4.z >> BSH], 1); packed[p] = (s4.z << BSH) | (d4.z & (BSZ - 1));
        p = atomicAdd(&cur[d4.w >> BSH], 1); packed[p] = (s4.w << BSH) | (d4.w & (BSZ - 1));
    }
}

// ===========================================================================
// BUILD stage 2 + FULL layer 0, fused. Per bucket:
//   pass 1: count per-node + d=1 aggregate (x gathers are L2-resident, 800KB)
//           + cache the bucket's packed edges in LDS (ECAP covers bucket size
//           at +15 sd; overflow falls back to global)
//   scan -> row_ptr; pass 2: in-place scatter sorted_src (aliases packed —
//           safe: pass 2 reads from the LDS cache, writes stay in-bucket)
//   fused layer-0 node update -> xa (no separate kernel, no 20MB re-read)
// ===========================================================================
__global__ void csr_fused_kernel(const float* __restrict__ x,
                                 const int* __restrict__ packed,
                                 const int* __restrict__ bucket_base,
                                 const float* __restrict__ Wl, const float* __restrict__ bl,
                                 const float* __restrict__ Wr,
                                 const float* __restrict__ Wlin, const float* __restrict__ blin,
                                 int* __restrict__ row_ptr,
                                 int* sorted_src,            // may alias packed
                                 float* __restrict__ xout) {
    __shared__ int sEdge[ECAP];                       // 16 KB
    __shared__ int cnt[BSZ], scn[BSZ], cur[BSZ];
    __shared__ float ssum[BSZ];
    __shared__ float sWl[HID], sWr[HID], sbl[HID], sblin[HID], sWlin[HID * HID];
    int t = threadIdx.x, b = blockIdx.x;
    if (t < BSZ) { cnt[t] = 0; ssum[t] = 0.0f; }
    if (t < HID) { sWl[t] = Wl[t]; sWr[t] = Wr[t]; sbl[t] = bl[t]; sblin[t] = blin[t]; }
    if (t < HID * HID) sWlin[t] = Wlin[t];
    __syncthreads();

    int e0 = bucket_base[b], e1 = bucket_base[b + 1];
    for (int i = e0 + t; i < e1; i += 256) {
        int pk = packed[i];
        int off = i - e0;
        if (off < ECAP) sEdge[off] = pk;
        int dl = pk & (BSZ - 1);
        atomicAdd(&cnt[dl], 1);
        atomicAdd(&ssum[dl], x[pk >> BSH]);
    }
    __syncthreads();
    if (t < BSZ) scn[t] = cnt[t];
    __syncthreads();
    for (int off = 1; off < BSZ; off <<= 1) {
        int v = 0;
        if (t < BSZ && t >= off) v = scn[t - off];
        __syncthreads();
        if (t < BSZ) scn[t] += v;
        __syncthreads();
    }
    int node = b * BSZ + t;
    if (t < BSZ) {
        int base = e0 + scn[t] - cnt[t];   // exclusive scan
        if (node < N_NODES) row_ptr[node] = base;
        cur[t] = base;
    }
    if (b == NB - 1 && t == 0) row_ptr[N_NODES] = N_EDGES;
    __syncthreads();

    // Pass 2: scatter within [e0,e1) — reads LDS cache, so in-place is safe.
    for (int i = e0 + t; i < e1; i += 256) {
        int off = i - e0;
        int pk = (off < ECAP) ? sEdge[off] : packed[i];
        int p = atomicAdd(&cur[pk & (BSZ - 1)], 1);
        sorted_src[p] = pk >> BSH;
    }

    // Fused layer-0 node update (needs only cnt/ssum — independent of pass 2)
    if (t < BSZ && node < N_NODES) {
        float mean = ssum[t] / fmaxf((float)cnt[t], 1.0f);
        float xv = x[node];
        float h[HID];
#pragma unroll
        for (int j = 0; j < HID; ++j)
            h[j] = fmaxf(mean * sWl[j] + sbl[j] + xv * sWr[j], 0.0f);
        float o[HID];
#pragma unroll
        for (int j = 0; j < HID; ++j) {
            float a = sblin[j];
#pragma unroll
            for (int k = 0; k < HID; ++k) a += h[k] * sWlin[k * HID + j];
            o[j] = a;
        }
        float4* op = reinterpret_cast<float4*>(xout + (size_t)node * HID);
#pragma unroll
        for (int q = 0; q < 4; ++q)
            op[q] = make_float4(o[q * 4 + 0], o[q * 4 + 1], o[q * 4 + 2], o[q * 4 + 3]);
    }
}

// ===========================================================================
// Layers 1/2 (d=16): 4-lane group per node, float4 register accumulation,
// 8 independent cache-line gathers in flight per group per iteration.
// Fused node update via LDS staging. 64 nodes per 256-thread block.
// (FROZEN from round 10: 110 us each, at the random-line BW floor)
// ===========================================================================
__global__ void layerB_csr(const float* __restrict__ xin,
                           const int* __restrict__ row_ptr,
                           const int* __restrict__ sorted_src,
                           const float* __restrict__ Wl, const float* __restrict__ bl,
                           const float* __restrict__ Wr,
                           const float* __restrict__ Wlin, const float* __restrict__ blin,
                           float* __restrict__ xout) {
    __shared__ float sacc[64 * SACCP];
    __shared__ float sxv[64 * SACCP];
    __shared__ float sh[64 * SACCP];
    __shared__ float sWl[HID * HID], sWr[HID * HID], sWlin[HID * HID];
    __shared__ float sbl[HID], sblin[HID];
    int t = threadIdx.x;
    if (t < HID * HID) { sWl[t] = Wl[t]; sWr[t] = Wr[t]; sWlin[t] = Wlin[t]; }
    if (t < HID) { sbl[t] = bl[t]; sblin[t] = blin[t]; }
    __syncthreads();

    int q = t & 3;           // feature quad: features 4q..4q+3
    int g = t >> 2;          // group 0..63 -> node
    int n = blockIdx.x * 64 + g;

    if (n < N_NODES) {
        int r0 = row_ptr[n], r1 = row_ptr[n + 1];
        const float* xq = xin + 4 * q;
        float4 acc = make_float4(0.0f, 0.0f, 0.0f, 0.0f);
        int i = r0;
        for (; i + 8 <= r1; i += 8) {
            int s0 = sorted_src[i],     s1 = sorted_src[i + 1];
            int s2 = sorted_src[i + 2], s3 = sorted_src[i + 3];
            int s4 = sorted_src[i + 4], s5 = sorted_src[i + 5];
            int s6 = sorted_src[i + 6], s7 = sorted_src[i + 7];
            float4 g0 = *reinterpret_cast<const float4*>(xq + (size_t)s0 * HID);
            float4 g1 = *reinterpret_cast<const float4*>(xq + (size_t)s1 * HID);
            float4 g2 = *reinterpret_cast<const float4*>(xq + (size_t)s2 * HID);
            float4 g3 = *reinterpret_cast<const float4*>(xq + (size_t)s3 * HID);
            float4 g4 = *reinterpret_cast<const float4*>(xq + (size_t)s4 * HID);
            float4 g5 = *reinterpret_cast<const float4*>(xq + (size_t)s5 * HID);
            float4 g6 = *reinterpret_cast<const float4*>(xq + (size_t)s6 * HID);
            float4 g7 = *reinterpret_cast<const float4*>(xq + (size_t)s7 * HID);
            acc.x += (g0.x + g1.x + g2.x + g3.x) + (g4.x + g5.x + g6.x + g7.x);
            acc.y += (g0.y + g1.y + g2.y + g3.y) + (g4.y + g5.y + g6.y + g7.y);
            acc.z += (g0.z + g1.z + g2.z + g3.z) + (g4.z + g5.z + g6.z + g7.z);
            acc.w += (g0.w + g1.w + g2.w + g3.w) + (g4.w + g5.w + g6.w + g7.w);
        }
        for (; i + 4 <= r1; i += 4) {
            int s0 = sorted_src[i],     s1 = sorted_src[i + 1];
            int s2 = sorted_src[i + 2], s3 = sorted_src[i + 3];
            float4 g0 = *reinterpret_cast<const float4*>(xq + (size_t)s0 * HID);
            float4 g1 = *reinterpret_cast<const float4*>(xq + (size_t)s1 * HID);
            float4 g2 = *reinterpret_cast<const float4*>(xq + (size_t)s2 * HID);
            float4 g3 = *reinterpret_cast<const float4*>(xq + (size_t)s3 * HID);
            acc.x += g0.x + g1.x + g2.x + g3.x;
            acc.y += g0.y + g1.y + g2.y + g3.y;
            acc.z += g0.z + g1.z + g2.z + g3.z;
            acc.w += g0.w + g1.w + g2.w + g3.w;
        }
        for (; i < r1; ++i) {
            float4 gv = *reinterpret_cast<const float4*>(xq + (size_t)sorted_src[i] * HID);
            acc.x += gv.x; acc.y += gv.y; acc.z += gv.z; acc.w += gv.w;
        }
        float invd = 1.0f / fmaxf((float)(r1 - r0), 1.0f);
        acc.x *= invd; acc.y *= invd; acc.z *= invd; acc.w *= invd;
        *reinterpret_cast<float4*>(&sacc[g * SACCP + 4 * q]) = acc;
        *reinterpret_cast<float4*>(&sxv[g * SACCP + 4 * q]) =
            *reinterpret_cast<const float4*>(xin + (size_t)n * HID + 4 * q);
    }
    __syncthreads();

    // U1: h[4q..4q+3] = relu(m@Wl + bl + xv@Wr)
    if (n < N_NODES) {
        float h4[4];
#pragma unroll
        for (int jj = 0; jj < 4; ++jj) {
            int j = 4 * q + jj;
            float a = sbl[j];
#pragma unroll
            for (int k = 0; k < HID; ++k)
                a += sacc[g * SACCP + k] * sWl[k * HID + j]
                   + sxv[g * SACCP + k] * sWr[k * HID + j];
            h4[jj] = fmaxf(a, 0.0f);
        }
        *reinterpret_cast<float4*>(&sh[g * SACCP + 4 * q]) =
            make_float4(h4[0], h4[1], h4[2], h4[3]);
    }
    __syncthreads();

    // U2: o[4q..4q+3] = h@Wlin + blin  -> coalesced store
    if (n < N_NODES) {
        float o4[4];
#pragma unroll
        for (int jj = 0; jj < 4; ++jj) {
            int j = 4 * q + jj;
            float a = sblin[j];
#pragma unroll
            for (int k = 0; k < HID; ++k) a += sh[g * SACCP + k] * sWlin[k * HID + j];
            o4[jj] = a;
        }
        *reinterpret_cast<float4*>(xout + (size_t)n * HID + 4 * q) =
            make_float4(o4[0], o4[1], o4[2], o4[3]);
    }
}

// ===========================================================================
// FALLBACK path (round-1, proven <=39.2MB): global-atomic scatter kernels
// ===========================================================================
__global__ void scatter0_kernel(const float* __restrict__ x,
                                const int* __restrict__ src,
                                const int* __restrict__ dst,
                                float* __restrict__ sum0,
                                float* __restrict__ deg) {
    int stride = gridDim.x * blockDim.x;
    for (int e = blockIdx.x * blockDim.x + threadIdx.x; e < N_EDGES; e += stride) {
        atomicAdd(&sum0[dst[e]], x[src[e]]);
        atomicAdd(&deg[dst[e]], 1.0f);
    }
}

__global__ void scatter16_kernel(const float* __restrict__ x,
                                 const int* __restrict__ src,
                                 const int* __restrict__ dst,
                                 float* __restrict__ summed) {
    int stride = gridDim.x * blockDim.x;
    const int total = N_EDGES * HID;
    for (int t = blockIdx.x * blockDim.x + threadIdx.x; t < total; t += stride) {
        int e = t >> 4, j = t & 15;
        atomicAdd(&summed[dst[e] * HID + j], x[src[e] * HID + j]);
    }
}

__global__ void node0_kernel(const float* __restrict__ x,
                             const float* __restrict__ sum0,
                             const float* __restrict__ deg,
                             const float* __restrict__ Wl, const float* __restrict__ bl,
                             const float* __restrict__ Wr,
                             const float* __restrict__ Wlin, const float* __restrict__ blin,
                             float* __restrict__ xout) {
    __shared__ float sWl[HID], sWr[HID], sbl[HID], sblin[HID], sWlin[HID * HID];
    if (threadIdx.x < HID) {
        sWl[threadIdx.x] = Wl[threadIdx.x]; sWr[threadIdx.x] = Wr[threadIdx.x];
        sbl[threadIdx.x] = bl[threadIdx.x]; sblin[threadIdx.x] = blin[threadIdx.x];
    }
    if (threadIdx.x < HID * HID) sWlin[threadIdx.x] = Wlin[threadIdx.x];
    __syncthreads();
    int stride = gridDim.x * blockDim.x;
    for (int n = blockIdx.x * blockDim.x + threadIdx.x; n < N_NODES; n += stride) {
        float mean = sum0[n] / fmaxf(deg[n], 1.0f);
        float xv = x[n];
        float h[HID];
#pragma unroll
        for (int j = 0; j < HID; ++j)
            h[j] = fmaxf(mean * sWl[j] + sbl[j] + xv * sWr[j], 0.0f);
#pragma unroll
        for (int j = 0; j < HID; ++j) {
            float acc = sblin[j];
#pragma unroll
            for (int k = 0; k < HID; ++k) acc += h[k] * sWlin[k * HID + j];
            xout[n * HID + j] = acc;
        }
    }
}

__global__ void node16_kernel(const float* __restrict__ xin,
                              const float* __restrict__ sums,
                              const float* __restrict__ deg,
                              const float* __restrict__ Wl, const float* __restrict__ bl,
                              const float* __restrict__ Wr,
                              const float* __restrict__ Wlin, const float* __restrict__ blin,
                              float* __restrict__ xout) {
    __shared__ float sWl[HID * HID], sWr[HID * HID], sWlin[HID * HID];
    __shared__ float sbl[HID], sblin[HID];
    if (threadIdx.x < HID * HID) {
        sWl[threadIdx.x] = Wl[threadIdx.x]; sWr[threadIdx.x] = Wr[threadIdx.x];
        sWlin[threadIdx.x] = Wlin[threadIdx.x];
    }
    if (threadIdx.x < HID) { sbl[threadIdx.x] = bl[threadIdx.x]; sblin[threadIdx.x] = blin[threadIdx.x]; }
    __syncthreads();
    int stride = gridDim.x * blockDim.x;
    for (int n = blockIdx.x * blockDim.x + threadIdx.x; n < N_NODES; n += stride) {
        float invd = 1.0f / fmaxf(deg[n], 1.0f);
        float m[HID], xv[HID];
        const float4* sp = reinterpret_cast<const float4*>(sums + (size_t)n * HID);
        const float4* xp = reinterpret_cast<const float4*>(xin + (size_t)n * HID);
#pragma unroll
        for (int qq = 0; qq < 4; ++qq) {
            float4 sv = sp[qq]; float4 vv = xp[qq];
            m[qq * 4 + 0] = sv.x * invd; m[qq * 4 + 1] = sv.y * invd;
            m[qq * 4 + 2] = sv.z * invd; m[qq * 4 + 3] = sv.w * invd;
            xv[qq * 4 + 0] = vv.x; xv[qq * 4 + 1] = vv.y; xv[qq * 4 + 2] = vv.z; xv[qq * 4 + 3] = vv.w;
        }
        float h[HID];
#pragma unroll
        for (int j = 0; j < HID; ++j) {
            float a = sbl[j];
#pragma unroll
            for (int k = 0; k < HID; ++k) a += m[k] * sWl[k * HID + j];
#pragma unroll
            for (int k = 0; k < HID; ++k) a += xv[k] * sWr[k * HID + j];
            h[j] = fmaxf(a, 0.0f);
        }
        float o[HID];
#pragma unroll
        for (int j = 0; j < HID; ++j) {
            float a = sblin[j];
#pragma unroll
            for (int k = 0; k < HID; ++k) a += h[k] * sWlin[k * HID + j];
            o[j] = a;
        }
        float4* op = reinterpret_cast<float4*>(xout + (size_t)n * HID);
#pragma unroll
        for (int qq = 0; qq < 4; ++qq)
            op[qq] = make_float4(o[qq * 4 + 0], o[qq * 4 + 1], o[qq * 4 + 2], o[qq * 4 + 3]);
    }
}

// ===========================================================================
// Attention pool + MLP head (batch sorted -> binary-searched range per graph)
// ===========================================================================
__global__ void pool_head_kernel(const float* __restrict__ x,
                                 const int* __restrict__ batch,
                                 const float* __restrict__ Wo0, const float* __restrict__ bo0,
                                 const float* __restrict__ Wo1, const float* __restrict__ bo1,
                                 const float* __restrict__ Wo2, const float* __restrict__ bo2,
                                 float* __restrict__ out) {
    int g = blockIdx.x;
    __shared__ int sRange[2];
    __shared__ float red_d[256], red_n[256];
    __shared__ float pooled[HID], h0[HID], h1[HID];

    if (threadIdx.x == 0) {
        int lo = 0, hi = N_NODES;
        while (lo < hi) { int mid = (lo + hi) >> 1; if (batch[mid] < g) lo = mid + 1; else hi = mid; }
        sRange[0] = lo;
        hi = N_NODES;
        while (lo < hi) { int mid = (lo + hi) >> 1; if (batch[mid] < g + 1) lo = mid + 1; else hi = mid; }
        sRange[1] = lo;
    }
    __syncthreads();
    int start = sRange[0], end = sRange[1];
    int j = threadIdx.x & 15;
    int sub = threadIdx.x >> 4;

    float dacc = 0.0f, nacc = 0.0f;
    for (int n = start + sub; n < end; n += 16) {
        float v = x[n * HID + j];
        float s = expf(ALPHA * v);
        dacc += s;
        nacc += s * v;
    }
    red_d[threadIdx.x] = dacc;
    red_n[threadIdx.x] = nacc;
    __syncthreads();

    if (threadIdx.x < HID) {
        float ds = 0.0f, ns = 0.0f;
        for (int k = 0; k < 16; ++k) {
            ds += red_d[k * 16 + threadIdx.x];
            ns += red_n[k * 16 + threadIdx.x];
        }
        pooled[threadIdx.x] = ds > 0.0f ? ns / ds : 0.0f;
    }
    __syncthreads();
    if (threadIdx.x < HID) {
        float acc = bo0[threadIdx.x];
        for (int k = 0; k < HID; ++k) acc += pooled[k] * Wo0[k * HID + threadIdx.x];
        h0[threadIdx.x] = fmaxf(acc, 0.0f);
    }
    __syncthreads();
    if (threadIdx.x < HID) {
        float acc = bo1[threadIdx.x];
        for (int k = 0; k < HID; ++k) acc += h0[k] * Wo1[k * HID + threadIdx.x];
        h1[threadIdx.x] = fmaxf(acc, 0.0f);
    }
    __syncthreads();
    if (threadIdx.x == 0) {
        float acc = bo2[0];
        for (int k = 0; k < HID; ++k) acc += h1[k] * Wo2[k];
        out[g] = acc;
    }
}

extern "C" void kernel_launch(void* const* d_in, const int* in_sizes, int n_in,
                              void* d_out, int out_size, void* d_ws, size_t ws_size,
                              hipStream_t stream) {
    const float* x      = (const float*)d_in[0];
    const int*   edge   = (const int*)d_in[1];
    const int*   batch  = (const int*)d_in[2];
    const float* Wl0    = (const float*)d_in[3];
    const float* bl0    = (const float*)d_in[4];
    const float* Wr0    = (const float*)d_in[5];
    const float* Wlin0  = (const float*)d_in[6];
    const float* blin0  = (const float*)d_in[7];
    const float* Wl1    = (const float*)d_in[8];
    const float* bl1    = (const float*)d_in[9];
    const float* Wr1    = (const float*)d_in[10];
    const float* Wlin1  = (const float*)d_in[11];
    const float* blin1  = (const float*)d_in[12];
    const float* Wl2    = (const float*)d_in[13];
    const float* bl2    = (const float*)d_in[14];
    const float* Wr2    = (const float*)d_in[15];
    const float* Wlin2  = (const float*)d_in[16];
    const float* blin2  = (const float*)d_in[17];
    const float* Wo0    = (const float*)d_in[18];
    const float* bo0    = (const float*)d_in[19];
    const float* Wo1    = (const float*)d_in[20];
    const float* bo1    = (const float*)d_in[21];
    const float* Wo2    = (const float*)d_in[22];
    const float* bo2    = (const float*)d_in[23];

    const int* src = edge;
    const int* dst = edge + N_EDGES;

    // ---- Workspace layout (main path), peak 48,000,528 B (unchanged) ----
    // sorted/packed[20MB in-place] | row_ptr[N+1] | M[NWGB*NB] | xa | xb
    // ct/bb alias inside xb region (dead before layerB writes xb).
    const size_t OFF_SORTED = 0;                                   // 20,000,000
    const size_t OFF_ROW    = 20000000;                            //    800,016
    const size_t OFF_M      = 20800016;                            //  1,600,512
    const size_t OFF_XA     = 22400528;                            // 12,800,000
    const size_t OFF_XB     = 35200528;                            // 12,800,000
    const size_t NEED_MAIN  = 48000528;
    const size_t OFF_CT     = 42400528;                            // inside xb
    const size_t OFF_BB     = 42406800;

    char* ws = (char*)d_ws;

    if (ws_size >= NEED_MAIN) {
        int*   packed      = (int*)(ws + OFF_SORTED);   // becomes sorted_src in place
        int*   sorted_src  = packed;
        int*   row_ptr     = (int*)(ws + OFF_ROW);
        int*   M           = (int*)(ws + OFF_M);
        float* xa          = (float*)(ws + OFF_XA);
        float* xb          = (float*)(ws + OFF_XB);
        int*   col_total   = (int*)(ws + OFF_CT);
        int*   bucket_base = (int*)(ws + OFF_BB);

        // Build: bucket sort
        count_kernel<<<NWGB, 1024, 0, stream>>>(dst, M);
        colscan_kernel<<<(NB + 255) / 256, 256, 0, stream>>>(M, col_total);
        bucketscan_kernel<<<1, 256, 0, stream>>>(col_total, bucket_base);
        scatter_build_kernel<<<NWGB, 1024, 0, stream>>>(src, dst, M, bucket_base, packed);
        // CSR finish + full layer 0 fused (in-place sort; xa written here)
        csr_fused_kernel<<<NB, 256, 0, stream>>>(x, packed, bucket_base,
                                                 Wl0, bl0, Wr0, Wlin0, blin0,
                                                 row_ptr, sorted_src, xa);

        // Layers 1/2
        layerB_csr<<<(N_NODES + 63) / 64, 256, 0, stream>>>(
            xa, row_ptr, sorted_src, Wl1, bl1, Wr1, Wlin1, blin1, xb);
        layerB_csr<<<(N_NODES + 63) / 64, 256, 0, stream>>>(
            xb, row_ptr, sorted_src, Wl2, bl2, Wr2, Wlin2, blin2, xa);

        pool_head_kernel<<<N_GRAPHS, 256, 0, stream>>>(xa, batch, Wo0, bo0, Wo1, bo1,
                                                       Wo2, bo2, (float*)d_out);
    } else {
        // ---- Fallback (round-1, proven 39.2 MB): global-atomic scatter ----
        float* deg    = (float*)ws;
        float* summed = deg + N_NODES;
        float* xa     = summed + (size_t)N_NODES * HID;
        float* xb     = xa + (size_t)N_NODES * HID;

        hipMemsetAsync(deg, 0, sizeof(float) * (size_t)N_NODES * (1 + HID), stream);
        scatter0_kernel<<<2048, 256, 0, stream>>>(x, src, dst, summed, deg);
        node0_kernel<<<784, 256, 0, stream>>>(x, summed, deg, Wl0, bl0, Wr0, Wlin0, blin0, xa);

        hipMemsetAsync(summed, 0, sizeof(float) * (size_t)N_NODES * HID, stream);
        scatter16_kernel<<<4096, 256, 0, stream>>>(xa, src, dst, summed);
        node16_kernel<<<784, 256, 0, stream>>>(xa, summed, deg, Wl1, bl1, Wr1, Wlin1, blin1, xb);

        hipMemsetAsync(summed, 0, sizeof(float) * (size_t)N_NODES * HID, stream);
        scatter16_kernel<<<4096, 256, 0, stream>>>(xb, src, dst, summed);
        node16_kernel<<<784, 256, 0, stream>>>(xb, summed, deg, Wl2, bl2, Wr2, Wlin2, blin2, xa);

        pool_head_kernel<<<N_GRAPHS, 256, 0, stream>>>(xa, batch, Wo0, bo0, Wo1, bo1,
                                                       Wo2, bo2, (float*)d_out);
    }
}